// Round 3
// baseline (102.838 us; speedup 1.0000x reference)
//
#include <hip/hip_runtime.h>
#include <hip/hip_bf16.h>

typedef __bf16 bf16x8 __attribute__((ext_vector_type(8)));
typedef float f32x4 __attribute__((ext_vector_type(4)));

#define MFMA16(a, b, c) __builtin_amdgcn_mfma_f32_16x16x32_bf16((a), (b), (c), 0, 0, 0)

// ---- constants ----
#define BATCH 8
#define SEQ 512
#define HID 768
#define NHEAD 12
#define HDIM 64
#define MTOT (BATCH * SEQ)   // 4096
#define NTOT (3 * HID)       // 2304

typedef const unsigned int __attribute__((address_space(1))) *gptr_t;
typedef unsigned int __attribute__((address_space(3))) *lptr_t;

__device__ __forceinline__ unsigned short f2bf(float f) {
    unsigned int u = __float_as_uint(f);
    u += 0x7fffu + ((u >> 16) & 1u);
    return (unsigned short)(u >> 16);
}

// ---- fused fp32 -> bf16 convert (hidden_states + 3 weights, one dispatch) ----
__global__ __launch_bounds__(256) void cvt_all_kernel(const float4* __restrict__ hs,
                                                      const float4* __restrict__ Wq,
                                                      const float4* __restrict__ Wk,
                                                      const float4* __restrict__ Wv,
                                                      ushort4* __restrict__ hsb,
                                                      ushort4* __restrict__ wb) {
    int i = blockIdx.x * 256 + threadIdx.x;
    float4 v;
    ushort4* dst;
    if (i < 786432) {
        v = hs[i];
        dst = hsb + i;
    } else {
        int j = i - 786432;
        int which = j / 147456;
        int jj = j - which * 147456;
        const float4* src = (which == 0) ? Wq : ((which == 1) ? Wk : Wv);
        v = src[jj];
        dst = wb + j;
    }
    ushort4 o;
    o.x = f2bf(v.x); o.y = f2bf(v.y); o.z = f2bf(v.z); o.w = f2bf(v.w);
    *dst = o;
}

// ---- fused QKV GEMM:  C[m, n] = sum_k hs[m,k] * W[n,k]  (n spans Wq|Wk|Wv rows) ----
__global__ __launch_bounds__(256) void qkv_gemm_kernel(const unsigned short* __restrict__ hsb,
                                                       const unsigned short* __restrict__ wb,
                                                       const float* __restrict__ bq,
                                                       const float* __restrict__ bk,
                                                       const float* __restrict__ bv,
                                                       unsigned short* __restrict__ Qb,
                                                       unsigned short* __restrict__ Kb,
                                                       unsigned short* __restrict__ VTb) {
    __shared__ __align__(16) unsigned short lsA[128 * 64];
    __shared__ __align__(16) unsigned short lsB[128 * 64];

    const int tid = threadIdx.x;
    const int w = tid >> 6;
    const int l = tid & 63;
    const int r16 = l & 15, g4 = l >> 4;
    const int wr = w >> 1, wc = w & 1;
    const int m0 = blockIdx.y * 128;
    const int n0 = blockIdx.x * 128;

    f32x4 acc[4][4];
#pragma unroll
    for (int i = 0; i < 4; ++i)
#pragma unroll
        for (int j = 0; j < 4; ++j)
            acc[i][j] = (f32x4){0.f, 0.f, 0.f, 0.f};

    for (int kt = 0; kt < 12; ++kt) {
        const int k0 = kt * 64;
        __syncthreads();
#pragma unroll
        for (int r = 0; r < 4; ++r) {
            int c = r * 256 + tid;              // 16B chunk index 0..1023
            int row = c >> 3;
            int cir = c & 7;
            const unsigned short* ga = hsb + (size_t)(m0 + row) * HID + k0 + cir * 8;
            __builtin_amdgcn_global_load_lds((gptr_t)(const void*)ga,
                                             (lptr_t)(void*)(lsA + (size_t)(r * 256 + w * 64) * 8),
                                             16, 0, 0);
            const unsigned short* gb = wb + (size_t)(n0 + row) * HID + k0 + cir * 8;
            __builtin_amdgcn_global_load_lds((gptr_t)(const void*)gb,
                                             (lptr_t)(void*)(lsB + (size_t)(r * 256 + w * 64) * 8),
                                             16, 0, 0);
        }
        __syncthreads();
#pragma unroll
        for (int kk = 0; kk < 64; kk += 32) {
            bf16x8 af[4], bfr[4];
#pragma unroll
            for (int mi = 0; mi < 4; ++mi)
                af[mi] = *reinterpret_cast<const bf16x8*>(&lsA[(wr * 64 + mi * 16 + r16) * 64 + kk + g4 * 8]);
#pragma unroll
            for (int ni = 0; ni < 4; ++ni)
                bfr[ni] = *reinterpret_cast<const bf16x8*>(&lsB[(wc * 64 + ni * 16 + r16) * 64 + kk + g4 * 8]);
#pragma unroll
            for (int mi = 0; mi < 4; ++mi)
#pragma unroll
                for (int ni = 0; ni < 4; ++ni)
                    acc[mi][ni] = MFMA16(af[mi], bfr[ni], acc[mi][ni]);
        }
    }

    // epilogue: bias add, Q pre-scale by 1/8, scatter to head layouts
#pragma unroll
    for (int ni = 0; ni < 4; ++ni) {
        int col = n0 + wc * 64 + ni * 16 + r16;   // 0..2303
        int which = col / HID;                    // 0=Q 1=K 2=V
        int oo = col - which * HID;
        int head = oo >> 6, d = oo & 63;
        const float* bias = (which == 0) ? bq : ((which == 1) ? bk : bv);
        float bvv = bias[oo];
#pragma unroll
        for (int mi = 0; mi < 4; ++mi) {
            int row0 = m0 + wr * 64 + mi * 16 + g4 * 4;   // 4-aligned, no batch straddle
            int bi = row0 >> 9;
            int s0 = row0 & 511;
            if (which == 2) {
                ushort4 pk;
                pk.x = f2bf(acc[mi][ni][0] + bvv);
                pk.y = f2bf(acc[mi][ni][1] + bvv);
                pk.z = f2bf(acc[mi][ni][2] + bvv);
                pk.w = f2bf(acc[mi][ni][3] + bvv);
                *reinterpret_cast<ushort4*>(
                    &VTb[((size_t)(bi * NHEAD + head) * HDIM + d) * SEQ + s0]) = pk;
            } else {
                unsigned short* dst = (which == 0) ? Qb : Kb;
                float scale = (which == 0) ? 0.125f : 1.0f;
#pragma unroll
                for (int r = 0; r < 4; ++r) {
                    dst[((size_t)(bi * NHEAD + head) * SEQ + (s0 + r)) * HDIM + d] =
                        f2bf((acc[mi][ni][r] + bvv) * scale);
                }
            }
        }
    }
}

// ---- attention: fused online-softmax over 4 KV-chunks of 128 ----
// Linear grid 768: id = qb*96 + (b*12+h)  => all 8 qb-blocks of one head share
// id mod 8 => same XCD => per-XCD K/VT working set 2.3 MB (L2-resident).
// Each chunk: preload ALL 16 K-fragments (one latency exposure), then MFMAs;
// same for PV's 16 VT-fragments.
__global__ __launch_bounds__(256, 3) void attn_kernel(const unsigned short* __restrict__ Qb,
                                                      const unsigned short* __restrict__ Kb,
                                                      const unsigned short* __restrict__ VTb,
                                                      const float* __restrict__ mask,
                                                      float* __restrict__ out) {
    __shared__ __align__(16) char pbuf_all[4 * 16 * 256];   // 16 KB total

    const int tid = threadIdx.x;
    const int w = tid >> 6;
    const int l = tid & 63;
    const int r16 = l & 15, g4 = l >> 4;

    const int id = blockIdx.x;          // 0..767
    const int hh = id % 96;             // head-group: same XCD for all qb
    const int qb = id / 96;             // 0..7
    const int b = hh / 12;
    const int h = hh % 12;

    const size_t headoff = ((size_t)b * NHEAD + h) * SEQ * HDIM;
    const size_t vtoff   = ((size_t)b * NHEAD + h) * HDIM * SEQ;
    const int q0 = qb * 64 + w * 16;
    char* pbuf = pbuf_all + (size_t)w * 16 * 256;

    // Q fragments (Q pre-scaled by 1/8 in GEMM epilogue)
    bf16x8 qa0 = *reinterpret_cast<const bf16x8*>(&Qb[headoff + (size_t)(q0 + r16) * HDIM + g4 * 8]);
    bf16x8 qa1 = *reinterpret_cast<const bf16x8*>(&Qb[headoff + (size_t)(q0 + r16) * HDIM + 32 + g4 * 8]);

    float m[4] = {-3.0e38f, -3.0e38f, -3.0e38f, -3.0e38f};
    float s[4] = {0.f, 0.f, 0.f, 0.f};
    f32x4 ct[4];
#pragma unroll
    for (int nt = 0; nt < 4; ++nt) ct[nt] = (f32x4){0.f, 0.f, 0.f, 0.f};

#pragma unroll 1
    for (int ch = 0; ch < 4; ++ch) {
        // --- preload mask + ALL K fragments for this 128-wide chunk ---
        float mv[8];
#pragma unroll
        for (int t = 0; t < 8; ++t)
            mv[t] = mask[b * SEQ + ch * 128 + t * 16 + r16];

        bf16x8 kf[8][2];
#pragma unroll
        for (int t = 0; t < 8; ++t) {
            int krow = ch * 128 + t * 16 + r16;
            kf[t][0] = *reinterpret_cast<const bf16x8*>(&Kb[headoff + (size_t)krow * HDIM + g4 * 8]);
            kf[t][1] = *reinterpret_cast<const bf16x8*>(&Kb[headoff + (size_t)krow * HDIM + 32 + g4 * 8]);
        }

        // --- scores: 8 tiles of 16x16 ---
        f32x4 sc[8];
#pragma unroll
        for (int t = 0; t < 8; ++t) {
            f32x4 c = {0.f, 0.f, 0.f, 0.f};
            c = MFMA16(qa0, kf[t][0], c);
            c = MFMA16(qa1, kf[t][1], c);
            c[0] += mv[t]; c[1] += mv[t]; c[2] += mv[t]; c[3] += mv[t];
            sc[t] = c;
        }

        // --- chunk max per q-row, reduce across the 16 k-lanes ---
        float pm[4] = {-3.0e38f, -3.0e38f, -3.0e38f, -3.0e38f};
#pragma unroll
        for (int t = 0; t < 8; ++t)
#pragma unroll
            for (int r = 0; r < 4; ++r)
                pm[r] = fmaxf(pm[r], sc[t][r]);
#pragma unroll
        for (int off = 1; off < 16; off <<= 1)
#pragma unroll
            for (int r = 0; r < 4; ++r)
                pm[r] = fmaxf(pm[r], __shfl_xor(pm[r], off));

        float f[4];
#pragma unroll
        for (int r = 0; r < 4; ++r) {
            float mn = fmaxf(m[r], pm[r]);
            f[r] = __expf(m[r] - mn);
            m[r] = mn;
        }

        // --- exp, partial row-sums, write P (bf16) to XOR-swizzled per-wave LDS ---
        float loc[4] = {0.f, 0.f, 0.f, 0.f};
#pragma unroll
        for (int t = 0; t < 8; ++t) {
#pragma unroll
            for (int r = 0; r < 4; ++r) {
                float p = __expf(sc[t][r] - m[r]);
                loc[r] += p;
                int q = g4 * 4 + r;
                int kk = t * 16 + r16;
                int byte = q * 256 + ((kk * 2) ^ ((q & 7) << 4));
                *reinterpret_cast<unsigned short*>(pbuf + byte) = f2bf(p);
            }
        }
#pragma unroll
        for (int r = 0; r < 4; ++r) s[r] = s[r] * f[r] + loc[r];

        // --- rescale running ctx ---
#pragma unroll
        for (int nt = 0; nt < 4; ++nt) {
            ct[nt][0] *= f[0]; ct[nt][1] *= f[1]; ct[nt][2] *= f[2]; ct[nt][3] *= f[3];
        }

        // --- PV: preload ALL 16 VT fragments, then MFMAs ---
        bf16x8 vb[4][4];   // [kt2][nt]
#pragma unroll
        for (int kt2 = 0; kt2 < 4; ++kt2)
#pragma unroll
            for (int nt = 0; nt < 4; ++nt)
                vb[kt2][nt] = *reinterpret_cast<const bf16x8*>(
                    &VTb[vtoff + (size_t)(nt * 16 + r16) * SEQ + ch * 128 + kt2 * 32 + g4 * 8]);

#pragma unroll
        for (int kt2 = 0; kt2 < 4; ++kt2) {
            int byte = r16 * 256 + ((kt2 * 64 + g4 * 16) ^ ((r16 & 7) << 4));
            bf16x8 pa = *reinterpret_cast<const bf16x8*>(pbuf + byte);
#pragma unroll
            for (int nt = 0; nt < 4; ++nt)
                ct[nt] = MFMA16(pa, vb[kt2][nt], ct[nt]);
        }
    }

    // --- final row-sum reduce + normalized output ---
#pragma unroll
    for (int off = 1; off < 16; off <<= 1)
#pragma unroll
        for (int r = 0; r < 4; ++r)
            s[r] += __shfl_xor(s[r], off);
    float rs[4];
#pragma unroll
    for (int r = 0; r < 4; ++r) rs[r] = 1.0f / s[r];

#pragma unroll
    for (int nt = 0; nt < 4; ++nt) {
#pragma unroll
        for (int r = 0; r < 4; ++r) {
            int srow = q0 + g4 * 4 + r;
            out[((size_t)b * SEQ + srow) * HID + h * HDIM + nt * 16 + r16] = ct[nt][r] * rs[r];
        }
    }
}

extern "C" void kernel_launch(void* const* d_in, const int* in_sizes, int n_in,
                              void* d_out, int out_size, void* d_ws, size_t ws_size,
                              hipStream_t stream) {
    const float* hs   = (const float*)d_in[0];
    const float* mask = (const float*)d_in[1];
    const float* Wq   = (const float*)d_in[2];
    const float* bq   = (const float*)d_in[3];
    const float* Wk   = (const float*)d_in[4];
    const float* bk   = (const float*)d_in[5];
    const float* Wv   = (const float*)d_in[6];
    const float* bv   = (const float*)d_in[7];
    float* out = (float*)d_out;

    char* ws = (char*)d_ws;
    // ws layout (bytes): hsb 6291456 | wb 3538944 | Q 6291456 | K 6291456 | VT 6291456
    unsigned short* hsb = (unsigned short*)(ws);
    unsigned short* wb  = (unsigned short*)(ws + 6291456);
    unsigned short* Qb  = (unsigned short*)(ws + 9830400);
    unsigned short* Kb  = (unsigned short*)(ws + 16121856);
    unsigned short* VTb = (unsigned short*)(ws + 22413312);

    // fused converts: 786432 + 442368 = 1228800 float4 chunks = 4800 blocks
    cvt_all_kernel<<<4800, 256, 0, stream>>>((const float4*)hs, (const float4*)Wq,
                                             (const float4*)Wk, (const float4*)Wv,
                                             (ushort4*)hsb, (ushort4*)wb);
    // fused QKV GEMM: grid = (N/128, M/128) = (18, 32)
    qkv_gemm_kernel<<<dim3(18, 32), 256, 0, stream>>>(hsb, wb, bq, bk, bv, Qb, Kb, VTb);
    // attention: linear grid 768 with XCD-grouping remap
    attn_kernel<<<768, 256, 0, stream>>>(Qb, Kb, VTb, mask, out);
}

// Round 5
// 82.655 us; speedup vs baseline: 1.2442x; 1.2442x over previous
//
#include <hip/hip_runtime.h>
#include <hip/hip_bf16.h>

typedef __bf16 bf16x8 __attribute__((ext_vector_type(8)));
typedef float f32x4 __attribute__((ext_vector_type(4)));
typedef float f32x16 __attribute__((ext_vector_type(16)));
typedef unsigned int u32x2 __attribute__((ext_vector_type(2)));
typedef unsigned int u32x4 __attribute__((ext_vector_type(4)));

#define MFMA16(a, b, c) __builtin_amdgcn_mfma_f32_16x16x32_bf16((a), (b), (c), 0, 0, 0)
#define MFMA32(a, b, c) __builtin_amdgcn_mfma_f32_32x32x16_bf16((a), (b), (c), 0, 0, 0)

// ---- constants ----
#define BATCH 8
#define SEQ 512
#define HID 768
#define NHEAD 12
#define HDIM 64

typedef const unsigned int __attribute__((address_space(1))) *gptr_t;
typedef unsigned int __attribute__((address_space(3))) *lptr_t;

__device__ __forceinline__ unsigned short f2bf(float f) {
    unsigned int u = __float_as_uint(f);
    u += 0x7fffu + ((u >> 16) & 1u);
    return (unsigned short)(u >> 16);
}

__device__ __forceinline__ unsigned int cvtpk_bf16(float lo, float hi) {
    unsigned int r;
    asm("v_cvt_pk_bf16_f32 %0, %1, %2" : "=v"(r) : "v"(lo), "v"(hi));
    return r;
}

// ---- fused fp32 -> bf16 convert (hidden_states + 3 weights, one dispatch) ----
__global__ __launch_bounds__(256) void cvt_all_kernel(const float4* __restrict__ hs,
                                                      const float4* __restrict__ Wq,
                                                      const float4* __restrict__ Wk,
                                                      const float4* __restrict__ Wv,
                                                      ushort4* __restrict__ hsb,
                                                      ushort4* __restrict__ wb) {
    int i = blockIdx.x * 256 + threadIdx.x;
    float4 v;
    ushort4* dst;
    if (i < 786432) {
        v = hs[i];
        dst = hsb + i;
    } else {
        int j = i - 786432;
        int which = j / 147456;
        int jj = j - which * 147456;
        const float4* src = (which == 0) ? Wq : ((which == 1) ? Wk : Wv);
        v = src[jj];
        dst = wb + j;
    }
    ushort4 o;
    o.x = f2bf(v.x); o.y = f2bf(v.y); o.z = f2bf(v.z); o.w = f2bf(v.w);
    *dst = o;
}

// ---- fused QKV GEMM (unchanged) ----
__global__ __launch_bounds__(256) void qkv_gemm_kernel(const unsigned short* __restrict__ hsb,
                                                       const unsigned short* __restrict__ wb,
                                                       const float* __restrict__ bq,
                                                       const float* __restrict__ bk,
                                                       const float* __restrict__ bv,
                                                       unsigned short* __restrict__ Qb,
                                                       unsigned short* __restrict__ Kb,
                                                       unsigned short* __restrict__ VTb) {
    __shared__ __align__(16) unsigned short lsA[128 * 64];
    __shared__ __align__(16) unsigned short lsB[128 * 64];

    const int tid = threadIdx.x;
    const int w = tid >> 6;
    const int l = tid & 63;
    const int r16 = l & 15, g4 = l >> 4;
    const int wr = w >> 1, wc = w & 1;
    const int m0 = blockIdx.y * 128;
    const int n0 = blockIdx.x * 128;

    f32x4 acc[4][4];
#pragma unroll
    for (int i = 0; i < 4; ++i)
#pragma unroll
        for (int j = 0; j < 4; ++j)
            acc[i][j] = (f32x4){0.f, 0.f, 0.f, 0.f};

    for (int kt = 0; kt < 12; ++kt) {
        const int k0 = kt * 64;
        __syncthreads();
#pragma unroll
        for (int r = 0; r < 4; ++r) {
            int c = r * 256 + tid;
            int row = c >> 3;
            int cir = c & 7;
            const unsigned short* ga = hsb + (size_t)(m0 + row) * HID + k0 + cir * 8;
            __builtin_amdgcn_global_load_lds((gptr_t)(const void*)ga,
                                             (lptr_t)(void*)(lsA + (size_t)(r * 256 + w * 64) * 8),
                                             16, 0, 0);
            const unsigned short* gb = wb + (size_t)(n0 + row) * HID + k0 + cir * 8;
            __builtin_amdgcn_global_load_lds((gptr_t)(const void*)gb,
                                             (lptr_t)(void*)(lsB + (size_t)(r * 256 + w * 64) * 8),
                                             16, 0, 0);
        }
        __syncthreads();
#pragma unroll
        for (int kk = 0; kk < 64; kk += 32) {
            bf16x8 af[4], bfr[4];
#pragma unroll
            for (int mi = 0; mi < 4; ++mi)
                af[mi] = *reinterpret_cast<const bf16x8*>(&lsA[(wr * 64 + mi * 16 + r16) * 64 + kk + g4 * 8]);
#pragma unroll
            for (int ni = 0; ni < 4; ++ni)
                bfr[ni] = *reinterpret_cast<const bf16x8*>(&lsB[(wc * 64 + ni * 16 + r16) * 64 + kk + g4 * 8]);
#pragma unroll
            for (int mi = 0; mi < 4; ++mi)
#pragma unroll
                for (int ni = 0; ni < 4; ++ni)
                    acc[mi][ni] = MFMA16(af[mi], bfr[ni], acc[mi][ni]);
        }
    }

#pragma unroll
    for (int ni = 0; ni < 4; ++ni) {
        int col = n0 + wc * 64 + ni * 16 + r16;
        int which = col / HID;
        int oo = col - which * HID;
        int head = oo >> 6, d = oo & 63;
        const float* bias = (which == 0) ? bq : ((which == 1) ? bk : bv);
        float bvv = bias[oo];
#pragma unroll
        for (int mi = 0; mi < 4; ++mi) {
            int row0 = m0 + wr * 64 + mi * 16 + g4 * 4;
            int bi = row0 >> 9;
            int s0 = row0 & 511;
            if (which == 2) {
                ushort4 pk;
                pk.x = f2bf(acc[mi][ni][0] + bvv);
                pk.y = f2bf(acc[mi][ni][1] + bvv);
                pk.z = f2bf(acc[mi][ni][2] + bvv);
                pk.w = f2bf(acc[mi][ni][3] + bvv);
                *reinterpret_cast<ushort4*>(
                    &VTb[((size_t)(bi * NHEAD + head) * HDIM + d) * SEQ + s0]) = pk;
            } else {
                unsigned short* dst = (which == 0) ? Qb : Kb;
                float scale = (which == 0) ? 0.125f : 1.0f;
#pragma unroll
                for (int r = 0; r < 4; ++r) {
                    dst[((size_t)(bi * NHEAD + head) * SEQ + (s0 + r)) * HDIM + d] =
                        f2bf((acc[mi][ni][r] + bvv) * scale);
                }
            }
        }
    }
}

// ---- attention v4b: swapped-QK^T 32x32 MFMA, in-register softmax (no max: scores tiny) ----
// Fixed permlane32_swap usage: HW swaps vdst.lanes[32:63] <-> src.lanes[0:31];
// swap(low-k word, high-k word) returns {frag word j, frag word j+2}.
__global__ __launch_bounds__(256, 3) void attn_kernel(const unsigned short* __restrict__ Qb,
                                                      const unsigned short* __restrict__ Kb,
                                                      const unsigned short* __restrict__ VTb,
                                                      const float* __restrict__ mask,
                                                      float* __restrict__ out) {
    __shared__ float lds_ctx[2][32][64];   // 16 KB
    __shared__ float lds_den[2][32];       // 256 B

    const int tid = threadIdx.x;
    const int w = tid >> 6;
    const int l = tid & 63;
    const int lq = l & 31;       // q-index (QK^T C-cols) / d-index (PV C-cols)
    const int h5 = l >> 5;       // wave half
    const int qg = w & 1;        // q-group within block
    const int kh = w >> 1;       // kv half

    const int id = blockIdx.x;   // 0..767
    const int hh = id % 96;      // same XCD for all qb of a head (96 % 8 == 0)
    const int qb = id / 96;
    const int b = hh / 12;
    const int hd = hh % 12;

    const size_t headoff = ((size_t)b * NHEAD + hd) * SEQ * HDIM;
    const size_t vtoff   = headoff;          // same extent, VT buffer
    const int q0 = qb * 64 + qg * 32;
    const float4* mask4 = (const float4*)mask;

    // Q B-fragments, hoisted: B[d][q], lane holds col q=lq, d = dc*16 + h5*8 + j
    bf16x8 qf[4];
#pragma unroll
    for (int dc = 0; dc < 4; ++dc)
        qf[dc] = *reinterpret_cast<const bf16x8*>(
            &Qb[headoff + (size_t)(q0 + lq) * HDIM + dc * 16 + h5 * 8]);

    f32x16 ctx0 = {};
    f32x16 ctx1 = {};
    float den = 0.f;

#pragma unroll 1
    for (int kb = 0; kb < 8; ++kb) {
        const int k0 = kh * 256 + kb * 32;

        // K A-fragments: A[ki][d], lane holds row ki=lq, d = dc*16 + h5*8 + j
        bf16x8 kf[4];
#pragma unroll
        for (int dc = 0; dc < 4; ++dc)
            kf[dc] = *reinterpret_cast<const bf16x8*>(
                &Kb[headoff + (size_t)(k0 + lq) * HDIM + dc * 16 + h5 * 8]);

        f32x16 T = {};
#pragma unroll
        for (int dc = 0; dc < 4; ++dc)
            T = MFMA32(kf[dc], qf[dc], T);

        // V B-fragments: B[k][d-tile n], lane col d = n*32+lq, k = k0 + c*16 + h5*8 + j
        bf16x8 vf00 = *reinterpret_cast<const bf16x8*>(&VTb[vtoff + (size_t)(lq) * SEQ + k0 + h5 * 8]);
        bf16x8 vf10 = *reinterpret_cast<const bf16x8*>(&VTb[vtoff + (size_t)(lq) * SEQ + k0 + 16 + h5 * 8]);
        bf16x8 vf01 = *reinterpret_cast<const bf16x8*>(&VTb[vtoff + (size_t)(32 + lq) * SEQ + k0 + h5 * 8]);
        bf16x8 vf11 = *reinterpret_cast<const bf16x8*>(&VTb[vtoff + (size_t)(32 + lq) * SEQ + k0 + 16 + h5 * 8]);

        // mask values for this lane's 16 k's: k = 8g + 4*h5 + (r&3)
        float4 mv[4];
#pragma unroll
        for (int g = 0; g < 4; ++g)
            mv[g] = mask4[b * 128 + (k0 >> 2) + 2 * g + h5];

        // p = exp(T + mask), accumulate denominator (all in-register)
        float p[16];
#pragma unroll
        for (int r = 0; r < 16; ++r) {
            float mval = (r & 3) == 0 ? mv[r >> 2].x : ((r & 3) == 1 ? mv[r >> 2].y
                       : ((r & 3) == 2 ? mv[r >> 2].z : mv[r >> 2].w));
            p[r] = __expf(T[r] + mval);
            den += p[r];
        }

        // pack p -> two bf16x8 A-fragments (k-chunks of 16) via cvt_pk + permlane32_swap.
        // swap(vdst, src): vdst.lanes[32:63] <-> src.lanes[0:31]; ret {vdst', src'}.
        // swap(low-word, high-word) -> ret[0] = frag word j (lo: own low, hi: partner low),
        //                              ret[1] = frag word j+2 (lo: partner high, hi: own high).
        bf16x8 pa[2];
#pragma unroll
        for (int c = 0; c < 2; ++c) {
            int base = c * 8;
            unsigned int lo01 = cvtpk_bf16(p[base + 0], p[base + 1]);  // h5=0: k(+0,+1) | h5=1: k(+4,+5)
            unsigned int lo23 = cvtpk_bf16(p[base + 2], p[base + 3]);  // h5=0: k(+2,+3) | h5=1: k(+6,+7)
            unsigned int hi01 = cvtpk_bf16(p[base + 4], p[base + 5]);  // h5=0: k(+8,+9) | h5=1: k(+12,+13)
            unsigned int hi23 = cvtpk_bf16(p[base + 6], p[base + 7]);  // h5=0: k(+10,+11)| h5=1: k(+14,+15)
            u32x2 s1 = __builtin_amdgcn_permlane32_swap(lo01, hi01, false, false);  // {w0, w2}
            u32x2 s2 = __builtin_amdgcn_permlane32_swap(lo23, hi23, false, false);  // {w1, w3}
            u32x4 words = {s1[0], s2[0], s1[1], s2[1]};
            pa[c] = __builtin_bit_cast(bf16x8, words);
        }

        ctx0 = MFMA32(pa[0], vf00, ctx0);
        ctx0 = MFMA32(pa[1], vf10, ctx0);
        ctx1 = MFMA32(pa[0], vf01, ctx1);
        ctx1 = MFMA32(pa[1], vf11, ctx1);
    }

    // combine the two lane-halves' denominator (each summed half of every k-line)
    float den_full = den + __shfl_xor(den, 32);

    if (kh == 1) {
        if (l < 32) lds_den[qg][l] = den_full;
#pragma unroll
        for (int r = 0; r < 16; ++r) {
            int qr = (r & 3) + 8 * (r >> 2) + 4 * h5;
            lds_ctx[qg][qr][lq] = ctx0[r];
            lds_ctx[qg][qr][32 + lq] = ctx1[r];
        }
    }
    __syncthreads();
    if (kh == 0) {
        float den_tot = den_full + lds_den[qg][lq];
#pragma unroll
        for (int r = 0; r < 16; ++r) {
            int qr = (r & 3) + 8 * (r >> 2) + 4 * h5;
            float dn = 1.0f / __shfl(den_tot, qr);
            size_t rowoff = ((size_t)b * SEQ + q0 + qr) * HID + hd * HDIM;
            out[rowoff + lq]      = (ctx0[r] + lds_ctx[qg][qr][lq]) * dn;
            out[rowoff + 32 + lq] = (ctx1[r] + lds_ctx[qg][qr][32 + lq]) * dn;
        }
    }
}

extern "C" void kernel_launch(void* const* d_in, const int* in_sizes, int n_in,
                              void* d_out, int out_size, void* d_ws, size_t ws_size,
                              hipStream_t stream) {
    const float* hs   = (const float*)d_in[0];
    const float* mask = (const float*)d_in[1];
    const float* Wq   = (const float*)d_in[2];
    const float* bq   = (const float*)d_in[3];
    const float* Wk   = (const float*)d_in[4];
    const float* bk   = (const float*)d_in[5];
    const float* Wv   = (const float*)d_in[6];
    const float* bv   = (const float*)d_in[7];
    float* out = (float*)d_out;

    char* ws = (char*)d_ws;
    unsigned short* hsb = (unsigned short*)(ws);
    unsigned short* wb  = (unsigned short*)(ws + 6291456);
    unsigned short* Qb  = (unsigned short*)(ws + 9830400);
    unsigned short* Kb  = (unsigned short*)(ws + 16121856);
    unsigned short* VTb = (unsigned short*)(ws + 22413312);

    cvt_all_kernel<<<4800, 256, 0, stream>>>((const float4*)hs, (const float4*)Wq,
                                             (const float4*)Wk, (const float4*)Wv,
                                             (ushort4*)hsb, (ushort4*)wb);
    qkv_gemm_kernel<<<dim3(18, 32), 256, 0, stream>>>(hsb, wb, bq, bk, bv, Qb, Kb, VTb);
    attn_kernel<<<768, 256, 0, stream>>>(Qb, Kb, VTb, mask, out);
}

// Round 6
// 78.369 us; speedup vs baseline: 1.3122x; 1.0547x over previous
//
#include <hip/hip_runtime.h>
#include <hip/hip_bf16.h>

typedef __bf16 bf16x8 __attribute__((ext_vector_type(8)));
typedef float f32x4 __attribute__((ext_vector_type(4)));
typedef float f32x16 __attribute__((ext_vector_type(16)));
typedef unsigned int u32x2 __attribute__((ext_vector_type(2)));
typedef unsigned int u32x4 __attribute__((ext_vector_type(4)));

#define MFMA16(a, b, c) __builtin_amdgcn_mfma_f32_16x16x32_bf16((a), (b), (c), 0, 0, 0)
#define MFMA32(a, b, c) __builtin_amdgcn_mfma_f32_32x32x16_bf16((a), (b), (c), 0, 0, 0)

// ---- constants ----
#define BATCH 8
#define SEQ 512
#define HID 768
#define NHEAD 12
#define HDIM 64

typedef const unsigned int __attribute__((address_space(1))) *gptr_t;
typedef unsigned int __attribute__((address_space(3))) *lptr_t;

__device__ __forceinline__ unsigned short f2bf(float f) {
    unsigned int u = __float_as_uint(f);
    u += 0x7fffu + ((u >> 16) & 1u);
    return (unsigned short)(u >> 16);
}

__device__ __forceinline__ unsigned int cvtpk_bf16(float lo, float hi) {
    unsigned int r;
    asm("v_cvt_pk_bf16_f32 %0, %1, %2" : "=v"(r) : "v"(lo), "v"(hi));
    return r;
}

// ---- fused fp32 -> bf16 convert (hidden_states + 3 weights, one dispatch) ----
__global__ __launch_bounds__(256) void cvt_all_kernel(const float4* __restrict__ hs,
                                                      const float4* __restrict__ Wq,
                                                      const float4* __restrict__ Wk,
                                                      const float4* __restrict__ Wv,
                                                      ushort4* __restrict__ hsb,
                                                      ushort4* __restrict__ wb) {
    int i = blockIdx.x * 256 + threadIdx.x;
    float4 v;
    ushort4* dst;
    if (i < 786432) {
        v = hs[i];
        dst = hsb + i;
    } else {
        int j = i - 786432;
        int which = j / 147456;
        int jj = j - which * 147456;
        const float4* src = (which == 0) ? Wq : ((which == 1) ? Wk : Wv);
        v = src[jj];
        dst = wb + j;
    }
    ushort4 o;
    o.x = f2bf(v.x); o.y = f2bf(v.y); o.z = f2bf(v.z); o.w = f2bf(v.w);
    *dst = o;
}

// ---- fused QKV GEMM v2: BK=32, double-buffered 2-phase pipeline, chunk-XOR swizzle ----
// C[m, n] = sum_k hs[m,k] * W[n,k]  (n spans Wq|Wk|Wv rows)
// 128x128 tile, 4 waves (2x2), each wave 64x64 via 4x4 MFMA 16x16x32.
// Swizzle (T2 via m173 pattern): LDS dest linear, global source chunk-XOR'd,
// ds_read at swizzled chunk -> 16-way bank conflict becomes 4-way.
__global__ __launch_bounds__(256) void qkv_gemm_kernel(const unsigned short* __restrict__ hsb,
                                                       const unsigned short* __restrict__ wb,
                                                       const float* __restrict__ bq,
                                                       const float* __restrict__ bk,
                                                       const float* __restrict__ bv,
                                                       unsigned short* __restrict__ Qb,
                                                       unsigned short* __restrict__ Kb,
                                                       unsigned short* __restrict__ VTb) {
    __shared__ __align__(16) unsigned short lsA[2][128 * 32];   // 16 KB
    __shared__ __align__(16) unsigned short lsB[2][128 * 32];   // 16 KB

    const int tid = threadIdx.x;
    const int w = tid >> 6;
    const int l = tid & 63;
    const int r16 = l & 15, g4 = l >> 4;
    const int wr = w >> 1, wc = w & 1;

    // XCD-aware remap: xcd = id&7 owns an 8Mx9N tile rectangle (A 1.6MB + B 1.8MB < 4MB L2)
    const int id = blockIdx.x;            // 0..575
    const int xcd = id & 7, j = id >> 3;  // j in [0,72) = 8 x 9
    const int tm = (xcd >> 1) * 8 + j / 9;   // 0..31
    const int tn = (xcd & 1) * 9 + j % 9;    // 0..17
    const int m0 = tm * 128;
    const int n0 = tn * 128;

    f32x4 acc[4][4];
#pragma unroll
    for (int i = 0; i < 4; ++i)
#pragma unroll
        for (int jj = 0; jj < 4; ++jj)
            acc[i][jj] = (f32x4){0.f, 0.f, 0.f, 0.f};

    // stage K-tile kt into buffer buf. Chunk c (16B) covers (row = c>>2, cc = c&3);
    // fetch global chunk (row, cc ^ (row&3)) so LDS slot s holds global chunk s^(row&3).
    auto stage = [&](int kt, int buf) {
        const int k0 = kt * 32;
#pragma unroll
        for (int r = 0; r < 2; ++r) {
            int c = r * 256 + tid;               // 0..511
            int row = c >> 2;
            int cc = (c & 3) ^ (row & 3);
            const unsigned short* ga = hsb + (size_t)(m0 + row) * HID + k0 + cc * 8;
            __builtin_amdgcn_global_load_lds((gptr_t)(const void*)ga,
                (lptr_t)(void*)(&lsA[buf][(size_t)(r * 256 + w * 64) * 8]), 16, 0, 0);
            const unsigned short* gb = wb + (size_t)(n0 + row) * HID + k0 + cc * 8;
            __builtin_amdgcn_global_load_lds((gptr_t)(const void*)gb,
                (lptr_t)(void*)(&lsB[buf][(size_t)(r * 256 + w * 64) * 8]), 16, 0, 0);
        }
    };

    stage(0, 0);
    __syncthreads();   // drains stage-0 (compiler emits vmcnt(0) before s_barrier)

#pragma unroll 1
    for (int kt = 0; kt < 24; ++kt) {
        const int cur = kt & 1;
        if (kt < 23) stage(kt + 1, cur ^ 1);   // loads fly during compute below

        bf16x8 af[4], bfr[4];
#pragma unroll
        for (int mi = 0; mi < 4; ++mi) {
            int row = wr * 64 + mi * 16 + r16;
            af[mi] = *reinterpret_cast<const bf16x8*>(
                &lsA[cur][row * 32 + ((g4 ^ (row & 3)) * 8)]);
        }
#pragma unroll
        for (int ni = 0; ni < 4; ++ni) {
            int row = wc * 64 + ni * 16 + r16;
            bfr[ni] = *reinterpret_cast<const bf16x8*>(
                &lsB[cur][row * 32 + ((g4 ^ (row & 3)) * 8)]);
        }
#pragma unroll
        for (int mi = 0; mi < 4; ++mi)
#pragma unroll
            for (int ni = 0; ni < 4; ++ni)
                acc[mi][ni] = MFMA16(af[mi], bfr[ni], acc[mi][ni]);

        __syncthreads();   // drains stage(kt+1) + protects buffer reuse
    }

    // epilogue: bias add, Q pre-scale by 1/8, scatter to head layouts
#pragma unroll
    for (int ni = 0; ni < 4; ++ni) {
        int col = n0 + wc * 64 + ni * 16 + r16;
        int which = col / HID;
        int oo = col - which * HID;
        int head = oo >> 6, d = oo & 63;
        const float* bias = (which == 0) ? bq : ((which == 1) ? bk : bv);
        float bvv = bias[oo];
#pragma unroll
        for (int mi = 0; mi < 4; ++mi) {
            int row0 = m0 + wr * 64 + mi * 16 + g4 * 4;
            int bi = row0 >> 9;
            int s0 = row0 & 511;
            if (which == 2) {
                ushort4 pk;
                pk.x = f2bf(acc[mi][ni][0] + bvv);
                pk.y = f2bf(acc[mi][ni][1] + bvv);
                pk.z = f2bf(acc[mi][ni][2] + bvv);
                pk.w = f2bf(acc[mi][ni][3] + bvv);
                *reinterpret_cast<ushort4*>(
                    &VTb[((size_t)(bi * NHEAD + head) * HDIM + d) * SEQ + s0]) = pk;
            } else {
                unsigned short* dst = (which == 0) ? Qb : Kb;
                float scale = (which == 0) ? 0.125f : 1.0f;
#pragma unroll
                for (int r = 0; r < 4; ++r) {
                    dst[((size_t)(bi * NHEAD + head) * SEQ + (s0 + r)) * HDIM + d] =
                        f2bf((acc[mi][ni][r] + bvv) * scale);
                }
            }
        }
    }
}

// ---- attention v4b (unchanged): swapped-QK^T 32x32 MFMA, in-register softmax ----
__global__ __launch_bounds__(256, 3) void attn_kernel(const unsigned short* __restrict__ Qb,
                                                      const unsigned short* __restrict__ Kb,
                                                      const unsigned short* __restrict__ VTb,
                                                      const float* __restrict__ mask,
                                                      float* __restrict__ out) {
    __shared__ float lds_ctx[2][32][64];   // 16 KB
    __shared__ float lds_den[2][32];       // 256 B

    const int tid = threadIdx.x;
    const int w = tid >> 6;
    const int l = tid & 63;
    const int lq = l & 31;
    const int h5 = l >> 5;
    const int qg = w & 1;
    const int kh = w >> 1;

    const int id = blockIdx.x;   // 0..767
    const int hh = id % 96;      // same XCD for all qb of a head (96 % 8 == 0)
    const int qb = id / 96;
    const int b = hh / 12;
    const int hd = hh % 12;

    const size_t headoff = ((size_t)b * NHEAD + hd) * SEQ * HDIM;
    const size_t vtoff   = headoff;
    const int q0 = qb * 64 + qg * 32;
    const float4* mask4 = (const float4*)mask;

    bf16x8 qf[4];
#pragma unroll
    for (int dc = 0; dc < 4; ++dc)
        qf[dc] = *reinterpret_cast<const bf16x8*>(
            &Qb[headoff + (size_t)(q0 + lq) * HDIM + dc * 16 + h5 * 8]);

    f32x16 ctx0 = {};
    f32x16 ctx1 = {};
    float den = 0.f;

#pragma unroll 1
    for (int kb = 0; kb < 8; ++kb) {
        const int k0 = kh * 256 + kb * 32;

        bf16x8 kf[4];
#pragma unroll
        for (int dc = 0; dc < 4; ++dc)
            kf[dc] = *reinterpret_cast<const bf16x8*>(
                &Kb[headoff + (size_t)(k0 + lq) * HDIM + dc * 16 + h5 * 8]);

        f32x16 T = {};
#pragma unroll
        for (int dc = 0; dc < 4; ++dc)
            T = MFMA32(kf[dc], qf[dc], T);

        bf16x8 vf00 = *reinterpret_cast<const bf16x8*>(&VTb[vtoff + (size_t)(lq) * SEQ + k0 + h5 * 8]);
        bf16x8 vf10 = *reinterpret_cast<const bf16x8*>(&VTb[vtoff + (size_t)(lq) * SEQ + k0 + 16 + h5 * 8]);
        bf16x8 vf01 = *reinterpret_cast<const bf16x8*>(&VTb[vtoff + (size_t)(32 + lq) * SEQ + k0 + h5 * 8]);
        bf16x8 vf11 = *reinterpret_cast<const bf16x8*>(&VTb[vtoff + (size_t)(32 + lq) * SEQ + k0 + 16 + h5 * 8]);

        float4 mv[4];
#pragma unroll
        for (int g = 0; g < 4; ++g)
            mv[g] = mask4[b * 128 + (k0 >> 2) + 2 * g + h5];

        float p[16];
#pragma unroll
        for (int r = 0; r < 16; ++r) {
            float mval = (r & 3) == 0 ? mv[r >> 2].x : ((r & 3) == 1 ? mv[r >> 2].y
                       : ((r & 3) == 2 ? mv[r >> 2].z : mv[r >> 2].w));
            p[r] = __expf(T[r] + mval);
            den += p[r];
        }

        bf16x8 pa[2];
#pragma unroll
        for (int c = 0; c < 2; ++c) {
            int base = c * 8;
            unsigned int lo01 = cvtpk_bf16(p[base + 0], p[base + 1]);
            unsigned int lo23 = cvtpk_bf16(p[base + 2], p[base + 3]);
            unsigned int hi01 = cvtpk_bf16(p[base + 4], p[base + 5]);
            unsigned int hi23 = cvtpk_bf16(p[base + 6], p[base + 7]);
            u32x2 s1 = __builtin_amdgcn_permlane32_swap(lo01, hi01, false, false);  // {w0, w2}
            u32x2 s2 = __builtin_amdgcn_permlane32_swap(lo23, hi23, false, false);  // {w1, w3}
            u32x4 words = {s1[0], s2[0], s1[1], s2[1]};
            pa[c] = __builtin_bit_cast(bf16x8, words);
        }

        ctx0 = MFMA32(pa[0], vf00, ctx0);
        ctx0 = MFMA32(pa[1], vf10, ctx0);
        ctx1 = MFMA32(pa[0], vf01, ctx1);
        ctx1 = MFMA32(pa[1], vf11, ctx1);
    }

    float den_full = den + __shfl_xor(den, 32);

    if (kh == 1) {
        if (l < 32) lds_den[qg][l] = den_full;
#pragma unroll
        for (int r = 0; r < 16; ++r) {
            int qr = (r & 3) + 8 * (r >> 2) + 4 * h5;
            lds_ctx[qg][qr][lq] = ctx0[r];
            lds_ctx[qg][qr][32 + lq] = ctx1[r];
        }
    }
    __syncthreads();
    if (kh == 0) {
        float den_tot = den_full + lds_den[qg][lq];
#pragma unroll
        for (int r = 0; r < 16; ++r) {
            int qr = (r & 3) + 8 * (r >> 2) + 4 * h5;
            float dn = 1.0f / __shfl(den_tot, qr);
            size_t rowoff = ((size_t)b * SEQ + q0 + qr) * HID + hd * HDIM;
            out[rowoff + lq]      = (ctx0[r] + lds_ctx[qg][qr][lq]) * dn;
            out[rowoff + 32 + lq] = (ctx1[r] + lds_ctx[qg][qr][32 + lq]) * dn;
        }
    }
}

extern "C" void kernel_launch(void* const* d_in, const int* in_sizes, int n_in,
                              void* d_out, int out_size, void* d_ws, size_t ws_size,
                              hipStream_t stream) {
    const float* hs   = (const float*)d_in[0];
    const float* mask = (const float*)d_in[1];
    const float* Wq   = (const float*)d_in[2];
    const float* bq   = (const float*)d_in[3];
    const float* Wk   = (const float*)d_in[4];
    const float* bk   = (const float*)d_in[5];
    const float* Wv   = (const float*)d_in[6];
    const float* bv   = (const float*)d_in[7];
    float* out = (float*)d_out;

    char* ws = (char*)d_ws;
    unsigned short* hsb = (unsigned short*)(ws);
    unsigned short* wb  = (unsigned short*)(ws + 6291456);
    unsigned short* Qb  = (unsigned short*)(ws + 9830400);
    unsigned short* Kb  = (unsigned short*)(ws + 16121856);
    unsigned short* VTb = (unsigned short*)(ws + 22413312);

    cvt_all_kernel<<<4800, 256, 0, stream>>>((const float4*)hs, (const float4*)Wq,
                                             (const float4*)Wk, (const float4*)Wv,
                                             (ushort4*)hsb, (ushort4*)wb);
    qkv_gemm_kernel<<<576, 256, 0, stream>>>(hsb, wb, bq, bk, bv, Qb, Kb, VTb);
    attn_kernel<<<768, 256, 0, stream>>>(Qb, Kb, VTb, mask, out);
}